// Round 5
// baseline (75.536 us; speedup 1.0000x reference)
//
#include <hip/hip_runtime.h>

#define EPS_F 1e-5f
#define BGRAPHS 4096
#define NPB 1024          // nodes per block in reduce/apply (256 thr * 4)
#define WIN 16            // S-window entries per block (covers >=16 id steps/chunk)
#define INF_I 0x7fffffff

// Detect whether the batch buffer is little-endian int64 viewed as int32.
// n is even; if int64, slot n-1 is a high word == 0; if int32, it's 4095 (sorted max).
__device__ __forceinline__ int batch_shift(const int* __restrict__ batch, int n) {
    return (batch[n - 1] == 0) ? 1 : 0;   // 1 -> stride-2 int32 reads (int64 data)
}

// S[b] = lower_bound(batch, b): first i with batch[i] >= b, for b in [0, BGRAPHS].
// batch is sorted, so S is non-decreasing; node i's graph = max g with S[g] <= i.
__global__ __launch_bounds__(256) void k_starts(const int* __restrict__ batch,
                                                int* __restrict__ S, int n)
{
    const int b = blockIdx.x * blockDim.x + threadIdx.x;
    if (b > BGRAPHS) return;
    const int shift = batch_shift(batch, n);
    int lo = 0, hi = n;
    while (lo < hi) {
        const int mid = (int)(((unsigned)lo + (unsigned)hi) >> 1);
        const int v = batch[(size_t)mid << shift];
        if (v < b) lo = mid + 1; else hi = mid;
    }
    S[b] = lo;
}

// cg[c] = max g in [0, BGRAPHS-1] with S[g] <= c*NPB  (coarse graph id per chunk)
__global__ __launch_bounds__(256) void k_coarse(const int* __restrict__ S,
                                                int* __restrict__ cg, int nchunks)
{
    const int c = blockIdx.x * blockDim.x + threadIdx.x;
    if (c >= nchunks) return;
    const int x = c * NPB;
    int lo = 0, hi = BGRAPHS - 1;
    #pragma unroll
    for (int s = 0; s < 12; ++s) {
        const int mid = (lo + hi + 1) >> 1;
        if (S[mid] <= x) lo = mid; else hi = mid - 1;
    }
    cg[c] = lo;
}

__global__ __launch_bounds__(256) void se3_reduce(
    const float* __restrict__ pos, const int* __restrict__ S, const int* __restrict__ cg,
    float* __restrict__ sums, float* __restrict__ cnts, int n)
{
    const int tid  = blockIdx.x * blockDim.x + threadIdx.x;
    const int base = tid * 4;
    const int lane = threadIdx.x & 63;

    // block-uniform window of segment starts (broadcast loads; L1-resident)
    const int g0 = cg[blockIdx.x];
    int w[WIN];
    #pragma unroll
    for (int k = 0; k < WIN; ++k) {
        const int idx = g0 + 1 + k;
        w[k] = (idx <= BGRAPHS) ? S[idx] : INF_I;   // S has BGRAPHS+1 entries, S[BGRAPHS]=n
    }

    int   cur_b = -1;
    float cur_s = 0.f, cur_c = 0.f;

    if (base < n) {
        float nrm[4];
        int   b4[4];
        const int nb = min(4, n - base);
        if (nb == 4) {
            const float4* p = reinterpret_cast<const float4*>(pos + (size_t)base * 3);
            const float4 a = p[0], b = p[1], c = p[2];
            nrm[0] = sqrtf(a.x * a.x + a.y * a.y + a.z * a.z);
            nrm[1] = sqrtf(a.w * a.w + b.x * b.x + b.y * b.y);
            nrm[2] = sqrtf(b.z * b.z + b.w * b.w + c.x * c.x);
            nrm[3] = sqrtf(c.y * c.y + c.z * c.z + c.w * c.w);
        } else {
            for (int j = 0; j < 4; ++j) nrm[j] = 0.f;
            for (int j = 0; j < nb; ++j) {
                const float x = pos[(size_t)(base + j) * 3 + 0];
                const float y = pos[(size_t)(base + j) * 3 + 1];
                const float z = pos[(size_t)(base + j) * 3 + 2];
                nrm[j] = sqrtf(x * x + y * y + z * z);
            }
        }
        // id resolution: g = max g' in [g0, g0+WIN] with S[g'] <= i  (pure VALU)
        #pragma unroll
        for (int j = 0; j < 4; ++j) {
            const int i = base + j;
            int g = g0;
            #pragma unroll
            for (int k = 0; k < WIN; ++k) g += (w[k] <= i) ? 1 : 0;
            b4[j] = (j < nb) ? g : -1;
        }
        // per-thread run accumulation (ids non-decreasing; boundaries rare)
        cur_b = b4[0];
        cur_s = nrm[0];
        cur_c = (b4[0] >= 0) ? 1.f : 0.f;
        #pragma unroll
        for (int j = 1; j < 4; ++j) {
            if (b4[j] == cur_b) { cur_s += nrm[j]; cur_c += 1.f; }
            else {
                if (cur_b >= 0) { atomicAdd(&sums[cur_b], cur_s); atomicAdd(&cnts[cur_b], cur_c); }
                cur_b = b4[j]; cur_s = nrm[j]; cur_c = (b4[j] >= 0) ? 1.f : 0.f;
            }
        }
    }

    // wave-level segmented reduction over each lane's last run (keys non-decreasing)
    #pragma unroll
    for (int off = 1; off < 64; off <<= 1) {
        const float os = __shfl_down(cur_s, off);
        const float oc = __shfl_down(cur_c, off);
        const int   ob = __shfl_down(cur_b, off);
        if (lane + off < 64 && ob == cur_b) { cur_s += os; cur_c += oc; }
    }
    const int pb = __shfl_up(cur_b, 1);
    if ((lane == 0 || pb != cur_b) && cur_b >= 0) {
        atomicAdd(&sums[cur_b], cur_s);
        atomicAdd(&cnts[cur_b], cur_c);
    }
}

__global__ void se3_finalize(const float* __restrict__ sums, const float* __restrict__ cnts,
                             const float* __restrict__ w, float* __restrict__ scale)
{
    const int b = blockIdx.x * blockDim.x + threadIdx.x;
    if (b < BGRAPHS) {
        const float mean = sums[b] / fmaxf(cnts[b], 1.f);
        scale[b] = w[0] / (mean + EPS_F);
    }
}

__global__ __launch_bounds__(256) void se3_apply(
    const float* __restrict__ pos, const int* __restrict__ S, const int* __restrict__ cg,
    const float* __restrict__ scale, float* __restrict__ out, int n)
{
    const int tid  = blockIdx.x * blockDim.x + threadIdx.x;
    const int base = tid * 4;
    if (base >= n) return;

    const int g0 = cg[blockIdx.x];
    int w[WIN];
    #pragma unroll
    for (int k = 0; k < WIN; ++k) {
        const int idx = g0 + 1 + k;
        w[k] = (idx <= BGRAPHS) ? S[idx] : INF_I;
    }

    float sc[4];
    #pragma unroll
    for (int j = 0; j < 4; ++j) {
        const int i = base + j;
        int g = g0;
        #pragma unroll
        for (int k = 0; k < WIN; ++k) g += (w[k] <= i) ? 1 : 0;
        sc[j] = scale[g];   // 16 KB table, L2-resident, wave-broadcast
    }

    if (base + 4 <= n) {
        const float4* p = reinterpret_cast<const float4*>(pos + (size_t)base * 3);
        const float4 a = p[0], b = p[1], c = p[2];
        float4* q = reinterpret_cast<float4*>(out + (size_t)base * 3);
        q[0] = make_float4(a.x * sc[0], a.y * sc[0], a.z * sc[0], a.w * sc[1]);
        q[1] = make_float4(b.x * sc[1], b.y * sc[1], b.z * sc[2], b.w * sc[2]);
        q[2] = make_float4(c.x * sc[2], c.y * sc[3], c.z * sc[3], c.w * sc[3]);
    } else {
        for (int j = 0; j < n - base; ++j) {
            out[(size_t)(base + j) * 3 + 0] = pos[(size_t)(base + j) * 3 + 0] * sc[j];
            out[(size_t)(base + j) * 3 + 1] = pos[(size_t)(base + j) * 3 + 1] * sc[j];
            out[(size_t)(base + j) * 3 + 2] = pos[(size_t)(base + j) * 3 + 2] * sc[j];
        }
    }
}

extern "C" void kernel_launch(void* const* d_in, const int* in_sizes, int n_in,
                              void* d_out, int out_size, void* d_ws, size_t ws_size,
                              hipStream_t stream)
{
    const float* pos   = (const float*)d_in[0];
    const int*   batch = (const int*)d_in[1];
    const float* w     = (const float*)d_in[2];
    float*       out   = (float*)d_out;
    const int    n     = in_sizes[1];

    float* sums  = (float*)d_ws;
    float* cnts  = sums + BGRAPHS;
    float* scale = cnts + BGRAPHS;
    int*   S     = (int*)(scale + BGRAPHS);      // BGRAPHS+1 entries
    int*   cg    = S + (BGRAPHS + 1);

    const int nthreads = (n + 3) / 4;
    const int blocks   = (nthreads + 255) / 256;  // chunks of NPB nodes

    // zero the accumulators every call (harness poisons ws once, never restores)
    hipMemsetAsync(d_ws, 0, 2 * BGRAPHS * sizeof(float), stream);

    k_starts<<<(BGRAPHS + 1 + 255) / 256, 256, 0, stream>>>(batch, S, n);
    k_coarse<<<(blocks + 255) / 256, 256, 0, stream>>>(S, cg, blocks);
    se3_reduce<<<blocks, 256, 0, stream>>>(pos, S, cg, sums, cnts, n);
    se3_finalize<<<(BGRAPHS + 255) / 256, 256, 0, stream>>>(sums, cnts, w, scale);
    se3_apply<<<blocks, 256, 0, stream>>>(pos, S, cg, scale, out, n);
}